// Round 1
// baseline (107.105 us; speedup 1.0000x reference)
//
#include <hip/hip_runtime.h>

#define NV 8
#define NB 16
#define LMAX 4096
#define ND 1024
#define CHUNK 64
#define NCHUNK (LMAX / CHUNK)   // 64 chunks -> 1024 blocks
#define GAMMA_ 10.0f
#define EPS_ 1e-6f

// ws layout: num[NB][NV][ND] floats, then den[NB][NV] floats
__global__ __launch_bounds__(256, 4) void dvs_accum(
    const float* __restrict__ v_pad,
    const float* __restrict__ centers,
    const int* __restrict__ grid_thws,
    float* __restrict__ ws_num,
    float* __restrict__ ws_den)
{
    const int b     = blockIdx.x / NCHUNK;
    const int chunk = blockIdx.x % NCHUNK;
    const int H  = grid_thws[b * 3 + 1];
    const int W  = grid_thws[b * 3 + 2];
    const int HW = H * W;
    const int l0 = chunk * CHUNK;
    if (l0 >= HW) return;                 // fully-masked chunk: read nothing
    const int l1 = min(l0 + CHUNK, HW);

    float cx[NV], cy[NV];
#pragma unroll
    for (int v = 0; v < NV; ++v) {
        float2 c = ((const float2*)centers)[b * NV + v];
        cx[v] = c.x; cy[v] = c.y;
    }
    const float invH = 1.0f / (float)H;
    const float invW = 1.0f / (float)W;

    const int t = threadIdx.x;            // thread owns d = 4t..4t+3
    const float4* __restrict__ src = (const float4*)(v_pad + (size_t)b * LMAX * ND);

    float acc[NV][4];
#pragma unroll
    for (int v = 0; v < NV; ++v)
#pragma unroll
        for (int k = 0; k < 4; ++k) acc[v][k] = 0.0f;
    float dsum[NV];
#pragma unroll
    for (int v = 0; v < NV; ++v) dsum[v] = 0.0f;

    // incremental (i,j) avoids per-row integer division
    int i = l0 / W;
    int j = l0 - i * W;

    float4 cur = src[(size_t)l0 * (ND / 4) + t];
    for (int l = l0; l < l1; ++l) {
        float4 nxt = cur;
        if (l + 1 < l1) nxt = src[(size_t)(l + 1) * (ND / 4) + t];  // prefetch
        const float y = ((float)i + 0.5f) * invH;
        const float x = ((float)j + 0.5f) * invW;
#pragma unroll
        for (int v = 0; v < NV; ++v) {
            const float dx = cx[v] - x;
            const float dy = cy[v] - y;
            const float m  = __expf(-GAMMA_ * (dx * dx + dy * dy));
            dsum[v] += m;
            acc[v][0] = fmaf(m, cur.x, acc[v][0]);
            acc[v][1] = fmaf(m, cur.y, acc[v][1]);
            acc[v][2] = fmaf(m, cur.z, acc[v][2]);
            acc[v][3] = fmaf(m, cur.w, acc[v][3]);
        }
        cur = nxt;
        if (++j == W) { j = 0; ++i; }
    }

    float* nb_ = ws_num + (size_t)(b * NV) * ND + t * 4;
#pragma unroll
    for (int v = 0; v < NV; ++v) {
        atomicAdd(nb_ + v * ND + 0, acc[v][0]);
        atomicAdd(nb_ + v * ND + 1, acc[v][1]);
        atomicAdd(nb_ + v * ND + 2, acc[v][2]);
        atomicAdd(nb_ + v * ND + 3, acc[v][3]);
    }
    if (t == 0) {
#pragma unroll
        for (int v = 0; v < NV; ++v) atomicAdd(&ws_den[b * NV + v], dsum[v]);
    }
}

__global__ __launch_bounds__(256) void dvs_final(
    const float* __restrict__ ws_num,
    const float* __restrict__ ws_den,
    float* __restrict__ out)
{
    const int idx = blockIdx.x * 256 + threadIdx.x;   // NB*NV*ND threads
    const int bv  = idx >> 10;                        // / ND
    out[idx] = ws_num[idx] / (ws_den[bv] + EPS_);
}

extern "C" void kernel_launch(void* const* d_in, const int* in_sizes, int n_in,
                              void* d_out, int out_size, void* d_ws, size_t ws_size,
                              hipStream_t stream) {
    const float* v_pad     = (const float*)d_in[0];
    const float* centers   = (const float*)d_in[1];
    // d_in[2] = v_len (== H*W), unused
    const int*   grid_thws = (const int*)d_in[3];

    float* ws_num = (float*)d_ws;
    float* ws_den = ws_num + (size_t)NB * NV * ND;

    hipMemsetAsync(d_ws, 0, ((size_t)NB * NV * ND + NB * NV) * sizeof(float), stream);

    dvs_accum<<<NB * NCHUNK, 256, 0, stream>>>(v_pad, centers, grid_thws, ws_num, ws_den);
    dvs_final<<<(NB * NV * ND) / 256, 256, 0, stream>>>(ws_num, ws_den, (float*)d_out);
}